// Round 2
// baseline (107.646 us; speedup 1.0000x reference)
//
#include <hip/hip_runtime.h>
#include <hip/hip_bf16.h>

// ---------------------------------------------------------------------------
// phi = (lam ⊙ (rho @ C^T)) @ C  with lam zero except k=1..256
//   => low-rank: A[b,kk] = Σ_n rho[b,n]·Ck[kk,n]   (kk=0..255, freq=kk+1)
//      phi[b,n] = Σ_kk (ms[kk]·A[b,kk])·Ck[kk,n]
// Ck[kk][n] = sqrt(2/4096)·cos(pi·(2n+1)·(kk+1)/8192)
// ---------------------------------------------------------------------------

using short8  = __attribute__((ext_vector_type(8))) short;     // 8 bf16 (4 VGPR)
using ushort8 = __attribute__((ext_vector_type(8))) unsigned short;
using ushort4v= __attribute__((ext_vector_type(4))) unsigned short;
using f32x4   = __attribute__((ext_vector_type(4))) float;

#define B_ROWS 1024
#define N_GRID 4096
#define R_MS   256
#define KSPLIT 8

static __device__ __forceinline__ unsigned short f32_to_bf16(float f) {
    union { float f; unsigned u; } v; v.f = f;
    unsigned u = v.u;
    u += 0x7FFFu + ((u >> 16) & 1u);   // round-to-nearest-even
    return (unsigned short)(u >> 16);
}

// ---------------------------------------------------------------------------
// Kernel 1: build bf16 DCT row tables.
//   Ck [256][4096]  (row = kk, freq = kk+1)
//   CkT[4096][256]  (transpose, for GEMM2's B-operand LDS staging)
// Exact angle reduction: m = (2n+1)(kk+1) mod 16384; angle = m * 2pi/16384.
// ---------------------------------------------------------------------------
__global__ __launch_bounds__(256) void build_tables(unsigned short* __restrict__ Ck,
                                                    unsigned short* __restrict__ CkT) {
    const float scale = 0.0220970869120796f;   // sqrt(2/4096)
    const float w     = 3.834951969714103e-4f; // 2*pi/16384
    int idx = blockIdx.x * 256 + threadIdx.x;  // 0 .. 2^20-1
    {   // coalesced Ck write
        int kk = idx >> 12, n = idx & 4095;
        int m = ((2 * n + 1) * (kk + 1)) & 16383;
        Ck[idx] = f32_to_bf16(scale * __cosf((float)m * w));
    }
    {   // coalesced CkT write (recompute cos; cheap)
        int n = idx >> 8, kk = idx & 255;
        int m = ((2 * n + 1) * (kk + 1)) & 16383;
        CkT[idx] = f32_to_bf16(scale * __cosf((float)m * w));
    }
}

// ---------------------------------------------------------------------------
// Kernel 2: GEMM1  partials[ks][b][kk] = Σ_{n in chunk} rho[b,n]·Ck[kk,n]
// grid (16,4,8): 64x64 tile per block, K-chunk 512, BK=32. 4 waves (2x2).
// ---------------------------------------------------------------------------
__global__ __launch_bounds__(256) void gemm1(const float* __restrict__ rho,
                                             const unsigned short* __restrict__ Ck,
                                             float* __restrict__ partials) {
    __shared__ unsigned short As[64][40];   // [m][k] bf16, pad->80B rows
    __shared__ unsigned short Bs[64][40];   // [kk][k(n)] bf16

    const int tid  = threadIdx.x;
    const int wave = tid >> 6, lane = tid & 63;
    const int wr = wave >> 1, wc = wave & 1;
    const int r = lane & 15, g = lane >> 4;
    const int bm0 = blockIdx.x * 64;       // batch rows
    const int bn0 = blockIdx.y * 64;       // kk cols
    const int kbase = blockIdx.z * 512;    // n chunk

    f32x4 acc[2][2];
    for (int i = 0; i < 2; ++i)
        for (int j = 0; j < 2; ++j)
            acc[i][j] = (f32x4){0.f, 0.f, 0.f, 0.f};

    for (int ks = 0; ks < 16; ++ks) {
        const int k0 = kbase + ks * 32;
        // stage A (rho f32 -> bf16) : 64 rows x 8 quarters(4 floats) = 512 slots
        #pragma unroll
        for (int s = 0; s < 2; ++s) {
            int slot = tid + s * 256;
            int row = slot >> 3, q = slot & 7;
            f32x4 v = *(const f32x4*)&rho[(size_t)(bm0 + row) * N_GRID + k0 + q * 4];
            ushort4v h;
            h[0] = f32_to_bf16(v[0]); h[1] = f32_to_bf16(v[1]);
            h[2] = f32_to_bf16(v[2]); h[3] = f32_to_bf16(v[3]);
            *(ushort4v*)&As[row][q * 4] = h;
        }
        // stage B (Ck rows kk, cols n-chunk): 64 rows x 8 quarters(4 bf16)
        #pragma unroll
        for (int s = 0; s < 2; ++s) {
            int slot = tid + s * 256;
            int row = slot >> 3, q = slot & 7;
            ushort4v h = *(const ushort4v*)&Ck[(size_t)(bn0 + row) * N_GRID + k0 + q * 4];
            *(ushort4v*)&Bs[row][q * 4] = h;
        }
        __syncthreads();
        short8 a0 = *(const short8*)&As[wr * 32 +  0 + r][g * 8];
        short8 a1 = *(const short8*)&As[wr * 32 + 16 + r][g * 8];
        short8 b0 = *(const short8*)&Bs[wc * 32 +  0 + r][g * 8];
        short8 b1 = *(const short8*)&Bs[wc * 32 + 16 + r][g * 8];
        acc[0][0] = __builtin_amdgcn_mfma_f32_16x16x32_bf16(a0, b0, acc[0][0], 0, 0, 0);
        acc[0][1] = __builtin_amdgcn_mfma_f32_16x16x32_bf16(a0, b1, acc[0][1], 0, 0, 0);
        acc[1][0] = __builtin_amdgcn_mfma_f32_16x16x32_bf16(a1, b0, acc[1][0], 0, 0, 0);
        acc[1][1] = __builtin_amdgcn_mfma_f32_16x16x32_bf16(a1, b1, acc[1][1], 0, 0, 0);
        __syncthreads();
    }

    // D layout: row=(lane>>4)*4+reg, col=lane&15  [verified m89]
    float* outp = partials + (size_t)blockIdx.z * (B_ROWS * R_MS);
    #pragma unroll
    for (int mi = 0; mi < 2; ++mi)
        #pragma unroll
        for (int ni = 0; ni < 2; ++ni)
            #pragma unroll
            for (int reg = 0; reg < 4; ++reg) {
                int row = bm0 + wr * 32 + mi * 16 + g * 4 + reg;
                int col = bn0 + wc * 32 + ni * 16 + r;
                outp[(size_t)row * R_MS + col] = acc[mi][ni][reg];
            }
}

// ---------------------------------------------------------------------------
// Kernel 3: reduce split-K partials, fold ms scale, emit bf16 Ascl[b][kk]
// ---------------------------------------------------------------------------
__global__ __launch_bounds__(256) void reduce_scale(const float* __restrict__ partials,
                                                    const float* __restrict__ ms,
                                                    unsigned short* __restrict__ Ascl) {
    int idx = blockIdx.x * 256 + threadIdx.x;   // 0..262143
    float s = 0.f;
    #pragma unroll
    for (int p = 0; p < KSPLIT; ++p)
        s += partials[(size_t)p * (B_ROWS * R_MS) + idx];
    int kk = idx & 255;
    Ascl[idx] = f32_to_bf16(s * ms[kk]);
}

// ---------------------------------------------------------------------------
// Kernel 4: GEMM2  phi[b][n] = Σ_kk Ascl[b,kk]·Ck[kk,n]
// grid (8,32): 128x128 tile, K=256, BK=32. 4 waves (2x2), 64x64 each.
// B-operand staged from CkT so LDS tile is [n][kk] (k-contiguous).
// Staging: 256 threads x 16 bf16 (two ushort8) = 4096 = 128x32.  <-- FIXED
// ---------------------------------------------------------------------------
__global__ __launch_bounds__(256) void gemm2(const unsigned short* __restrict__ Ascl,
                                             const unsigned short* __restrict__ CkT,
                                             float* __restrict__ phi) {
    __shared__ unsigned short As[128][40];  // [b][kk]
    __shared__ unsigned short Bs[128][40];  // [n][kk]

    const int tid  = threadIdx.x;
    const int wave = tid >> 6, lane = tid & 63;
    const int wr = wave >> 1, wc = wave & 1;
    const int r = lane & 15, g = lane >> 4;
    const int bm0 = blockIdx.x * 128;   // batch rows
    const int bn0 = blockIdx.y * 128;   // n cols

    f32x4 acc[4][4];
    #pragma unroll
    for (int i = 0; i < 4; ++i)
        #pragma unroll
        for (int j = 0; j < 4; ++j)
            acc[i][j] = (f32x4){0.f, 0.f, 0.f, 0.f};

    const int srow = tid & 127, spart = tid >> 7;   // 128 rows x 2 halves x 16 bf16

    for (int ks = 0; ks < 8; ++ks) {
        const int k0 = ks * 32;
        {
            const ushort8* pA = (const ushort8*)&Ascl[(size_t)(bm0 + srow) * R_MS + k0 + spart * 16];
            *(ushort8*)&As[srow][spart * 16]     = pA[0];
            *(ushort8*)&As[srow][spart * 16 + 8] = pA[1];
            const ushort8* pB = (const ushort8*)&CkT[(size_t)(bn0 + srow) * R_MS + k0 + spart * 16];
            *(ushort8*)&Bs[srow][spart * 16]     = pB[0];
            *(ushort8*)&Bs[srow][spart * 16 + 8] = pB[1];
        }
        __syncthreads();
        short8 a[4], b[4];
        #pragma unroll
        for (int mi = 0; mi < 4; ++mi)
            a[mi] = *(const short8*)&As[wr * 64 + mi * 16 + r][g * 8];
        #pragma unroll
        for (int ni = 0; ni < 4; ++ni)
            b[ni] = *(const short8*)&Bs[wc * 64 + ni * 16 + r][g * 8];
        #pragma unroll
        for (int mi = 0; mi < 4; ++mi)
            #pragma unroll
            for (int ni = 0; ni < 4; ++ni)
                acc[mi][ni] = __builtin_amdgcn_mfma_f32_16x16x32_bf16(a[mi], b[ni], acc[mi][ni], 0, 0, 0);
        __syncthreads();
    }

    #pragma unroll
    for (int mi = 0; mi < 4; ++mi)
        #pragma unroll
        for (int ni = 0; ni < 4; ++ni)
            #pragma unroll
            for (int reg = 0; reg < 4; ++reg) {
                int row = bm0 + wr * 64 + mi * 16 + g * 4 + reg;
                int col = bn0 + wc * 64 + ni * 16 + r;
                phi[(size_t)row * N_GRID + col] = acc[mi][ni][reg];
            }
}

// ---------------------------------------------------------------------------
extern "C" void kernel_launch(void* const* d_in, const int* in_sizes, int n_in,
                              void* d_out, int out_size, void* d_ws, size_t ws_size,
                              hipStream_t stream) {
    const float* rho = (const float*)d_in[0];   // [1024][4096] f32
    const float* ms  = (const float*)d_in[1];   // [256] f32
    float* phi = (float*)d_out;                 // [1024][4096] f32

    // Workspace: only tables + Ascl (4.5 MB). Split-K partials (8 MB) live in
    // d_out: written by gemm1, consumed by reduce_scale, then overwritten by
    // gemm2's final phi. Strictly sequential on one stream -> safe.
    char* ws = (char*)d_ws;
    unsigned short* Ck   = (unsigned short*)(ws);               // 2 MB
    unsigned short* CkT  = (unsigned short*)(ws + (2u << 20));  // 2 MB
    unsigned short* Ascl = (unsigned short*)(ws + (4u << 20));  // 0.5 MB
    float* partials = (float*)d_out;                            // 8 MB of 16 MB

    build_tables<<<4096, 256, 0, stream>>>(Ck, CkT);
    gemm1<<<dim3(16, 4, 8), 256, 0, stream>>>(rho, Ck, partials);
    reduce_scale<<<1024, 256, 0, stream>>>(partials, ms, Ascl);
    gemm2<<<dim3(8, 32), 256, 0, stream>>>(Ascl, CkT, phi);
}

// Round 3
// 90.428 us; speedup vs baseline: 1.1904x; 1.1904x over previous
//
#include <hip/hip_runtime.h>
#include <hip/hip_bf16.h>

// ---------------------------------------------------------------------------
// phi = (lam ⊙ (rho @ C^T)) @ C, lam zero except k=1..256  => rank-256:
//   A[b,kk]  = Σ_n rho[b,n]·Ck[kk,n]        (kk=0..255, freq=kk+1)
//   phi[b,n] = Σ_kk A[b,kk]·(ms[kk]·Ck[kk,n])
// Ck[kk][n] = sqrt(2/4096)·cos(pi·(2n+1)·(kk+1)/8192)
//
// All GEMM operands are stored PRE-PACKED in MFMA fragment order:
//   P[tile][kslice][lane][8 bf16]   (1 KB per wave-load, lane*16B coalesced)
// Fragment conventions (HW-verified m89, reused from the passing round-2 run):
//   A-frag lane(r=lane&15, g=lane>>4) holds A[row=r][k=g*8+j]
//   B-frag lane(r,g)              holds B[k=g*8+j][col=r]
//   D     lane reg                holds D[row=g*4+reg][col=r]
// => both GEMMs are LDS-free, barrier-free, pure-register MFMA loops.
// ---------------------------------------------------------------------------

using short8  = __attribute__((ext_vector_type(8))) short;
using ushort8 = __attribute__((ext_vector_type(8))) unsigned short;
using ushort4v= __attribute__((ext_vector_type(4))) unsigned short;
using f32x4   = __attribute__((ext_vector_type(4))) float;

#define KSPLIT 16

static __device__ __forceinline__ unsigned short f32_to_bf16(float f) {
    union { float f; unsigned u; } v; v.f = f;
    unsigned u = v.u;
    u += 0x7FFFu + ((u >> 16) & 1u);   // RNE
    return (unsigned short)(u >> 16);
}

#define DCT_SCALE 0.0220970869120796f     /* sqrt(2/4096) */
#define DCT_W     3.834951969714103e-4f   /* 2*pi/16384   */

// ---------------------------------------------------------------------------
// K1: build packed tables + pack rho.
//  PA1[tma=64][ns=128][lane][8] = bf16(rho[tma*16+r][ns*32+g*8+j])
//  PB1[t=16 ][ns=128][lane][8] = bf16(Ck[t*16+r][ns*32+g*8+j])          (B of GEMM1)
//  PB2[tn=256][ks=8 ][lane][8] = bf16(ms[ks*32+g*8+j]·Ck[..][tn*16+r])  (B of GEMM2)
// grid 3072x256: blocks [0,2048) PA1, [2048,2560) PB1, [2560,3072) PB2.
// ---------------------------------------------------------------------------
__global__ __launch_bounds__(256) void build_pack(const float* __restrict__ rho,
                                                  const float* __restrict__ ms,
                                                  unsigned short* __restrict__ PA1,
                                                  unsigned short* __restrict__ PB1,
                                                  unsigned short* __restrict__ PB2) {
    const int bid = blockIdx.x, tid = threadIdx.x;
    if (bid < 2048) {          // ---- PA1: pack rho -> bf16 fragments
        int o8   = bid * 256 + tid;            // 0 .. 524287
        int lane = o8 & 63;
        int ns   = (o8 >> 6) & 127;
        int tma  = o8 >> 13;
        int row  = tma * 16 + (lane & 15);
        int n0   = ns * 32 + (lane >> 4) * 8;
        const float* p = rho + (size_t)row * 4096 + n0;
        f32x4 v0 = *(const f32x4*)p;
        f32x4 v1 = *(const f32x4*)(p + 4);
        ushort8 h;
        h[0] = f32_to_bf16(v0[0]); h[1] = f32_to_bf16(v0[1]);
        h[2] = f32_to_bf16(v0[2]); h[3] = f32_to_bf16(v0[3]);
        h[4] = f32_to_bf16(v1[0]); h[5] = f32_to_bf16(v1[1]);
        h[6] = f32_to_bf16(v1[2]); h[7] = f32_to_bf16(v1[3]);
        *(ushort8*)(PA1 + (size_t)o8 * 8) = h;
    } else if (bid < 2560) {   // ---- PB1: Ck fragments for GEMM1
        int o8   = (bid - 2048) * 256 + tid;   // 0 .. 131071
        int lane = o8 & 63;
        int ns   = (o8 >> 6) & 127;
        int t    = o8 >> 13;
        int kk   = t * 16 + (lane & 15);
        int nb   = ns * 32 + (lane >> 4) * 8;
        ushort8 h;
        #pragma unroll
        for (int j = 0; j < 8; ++j) {
            int n = nb + j;
            int m = ((2 * n + 1) * (kk + 1)) & 16383;
            h[j] = f32_to_bf16(DCT_SCALE * __cosf((float)m * DCT_W));
        }
        *(ushort8*)(PB1 + (size_t)o8 * 8) = h;
    } else {                   // ---- PB2: (ms·Ck) fragments for GEMM2
        int o8   = (bid - 2560) * 256 + tid;   // 0 .. 131071
        int lane = o8 & 63;
        int ks   = (o8 >> 6) & 7;
        int tn   = o8 >> 9;
        int n    = tn * 16 + (lane & 15);
        int kb   = ks * 32 + (lane >> 4) * 8;
        f32x4 m0 = *(const f32x4*)(ms + kb);
        f32x4 m1 = *(const f32x4*)(ms + kb + 4);
        ushort8 h;
        #pragma unroll
        for (int j = 0; j < 8; ++j) {
            int kk = kb + j;
            int m  = ((2 * n + 1) * (kk + 1)) & 16383;
            float msv = (j < 4) ? m0[j & 3] : m1[j & 3];
            h[j] = f32_to_bf16(msv * DCT_SCALE * __cosf((float)m * DCT_W));
        }
        *(ushort8*)(PB2 + (size_t)o8 * 8) = h;
    }
}

// ---------------------------------------------------------------------------
// K2: GEMM1  partials[z][b][kk] = Σ_{n in chunk z} rho[b,n]·Ck[kk,n]
// grid (16,16) x 512 thr: block = 64 rows x 256 kk, K-chunk 256 (8 x BK32).
// 8 waves (2M x 4N), each 32x64 out. Pure-register, no LDS, no barriers.
// ---------------------------------------------------------------------------
__global__ __launch_bounds__(512) void gemm1(const unsigned short* __restrict__ PA1,
                                             const unsigned short* __restrict__ PB1,
                                             float* __restrict__ partials) {
    const int tid  = threadIdx.x;
    const int wave = tid >> 6, lane = tid & 63;
    const int wm = wave >> 2, wn = wave & 3;
    const int r = lane & 15, g = lane >> 4;
    const int z = blockIdx.y;
    const int tma0 = blockIdx.x * 4 + wm * 2;

    f32x4 acc[2][4];
    #pragma unroll
    for (int i = 0; i < 2; ++i)
        #pragma unroll
        for (int j = 0; j < 4; ++j)
            acc[i][j] = (f32x4){0.f, 0.f, 0.f, 0.f};

    #pragma unroll 2
    for (int ks = 0; ks < 8; ++ks) {
        const int ns = z * 8 + ks;
        short8 a[2], b[4];
        #pragma unroll
        for (int mi = 0; mi < 2; ++mi)
            a[mi] = *(const short8*)(PA1 + (((size_t)(tma0 + mi) * 128 + ns) * 64 + lane) * 8);
        #pragma unroll
        for (int ni = 0; ni < 4; ++ni) {
            int t = wn * 4 + ni;
            b[ni] = *(const short8*)(PB1 + (((size_t)t * 128 + ns) * 64 + lane) * 8);
        }
        #pragma unroll
        for (int mi = 0; mi < 2; ++mi)
            #pragma unroll
            for (int ni = 0; ni < 4; ++ni)
                acc[mi][ni] = __builtin_amdgcn_mfma_f32_16x16x32_bf16(a[mi], b[ni], acc[mi][ni], 0, 0, 0);
    }

    float* outp = partials + (size_t)z * 262144;
    #pragma unroll
    for (int mi = 0; mi < 2; ++mi)
        #pragma unroll
        for (int ni = 0; ni < 4; ++ni)
            #pragma unroll
            for (int reg = 0; reg < 4; ++reg) {
                int row = (tma0 + mi) * 16 + g * 4 + reg;
                int col = (wn * 4 + ni) * 16 + r;
                outp[(size_t)row * 256 + col] = acc[mi][ni][reg];
            }
}

// ---------------------------------------------------------------------------
// K3: reduce split-K partials -> PA2 packed bf16 (ms folded into PB2).
//  PA2[tma=64][ks=8][lane][8] = bf16(Σ_z partials[z][tma*16+r][ks*32+g*8+j])
// Coalesced f32x4 reads; scattered 8B packed writes (only 0.5 MB).
// ---------------------------------------------------------------------------
__global__ __launch_bounds__(256) void reduce_pack(const float* __restrict__ partials,
                                                   unsigned short* __restrict__ PA2) {
    int idx = blockIdx.x * 256 + threadIdx.x;  // 0..65535
    int kk4 = idx & 63, b = idx >> 6;
    int kk  = kk4 * 4;
    f32x4 s = (f32x4){0.f, 0.f, 0.f, 0.f};
    #pragma unroll
    for (int z = 0; z < KSPLIT; ++z)
        s += *(const f32x4*)(partials + (size_t)z * 262144 + (size_t)b * 256 + kk);
    int tma = b >> 4, r = b & 15;
    int ks = kk >> 5, rem = kk & 31, g = rem >> 3, h = (rem >> 2) & 1;
    size_t slot = (((size_t)tma * 8 + ks) * 64 + g * 16 + r) * 8 + h * 4;
    ushort4v o;
    o[0] = f32_to_bf16(s[0]); o[1] = f32_to_bf16(s[1]);
    o[2] = f32_to_bf16(s[2]); o[3] = f32_to_bf16(s[3]);
    *(ushort4v*)(PA2 + slot) = o;
}

// ---------------------------------------------------------------------------
// K4: GEMM2  phi[b][n] = Σ_kk A[b,kk]·(ms·Ck)[kk,n]
// grid (16,16) x 512 thr: block = 64 rows x 256 n-cols, K=256 (8 x BK32).
// Pure-register, no LDS, no barriers.
// ---------------------------------------------------------------------------
__global__ __launch_bounds__(512) void gemm2(const unsigned short* __restrict__ PA2,
                                             const unsigned short* __restrict__ PB2,
                                             float* __restrict__ phi) {
    const int tid  = threadIdx.x;
    const int wave = tid >> 6, lane = tid & 63;
    const int wm = wave >> 2, wn = wave & 3;
    const int r = lane & 15, g = lane >> 4;
    const int tma0 = blockIdx.x * 4 + wm * 2;
    const int tn0  = blockIdx.y * 16 + wn * 4;

    f32x4 acc[2][4];
    #pragma unroll
    for (int i = 0; i < 2; ++i)
        #pragma unroll
        for (int j = 0; j < 4; ++j)
            acc[i][j] = (f32x4){0.f, 0.f, 0.f, 0.f};

    #pragma unroll 2
    for (int ks = 0; ks < 8; ++ks) {
        short8 a[2], b[4];
        #pragma unroll
        for (int mi = 0; mi < 2; ++mi)
            a[mi] = *(const short8*)(PA2 + (((size_t)(tma0 + mi) * 8 + ks) * 64 + lane) * 8);
        #pragma unroll
        for (int ni = 0; ni < 4; ++ni)
            b[ni] = *(const short8*)(PB2 + (((size_t)(tn0 + ni) * 8 + ks) * 64 + lane) * 8);
        #pragma unroll
        for (int mi = 0; mi < 2; ++mi)
            #pragma unroll
            for (int ni = 0; ni < 4; ++ni)
                acc[mi][ni] = __builtin_amdgcn_mfma_f32_16x16x32_bf16(a[mi], b[ni], acc[mi][ni], 0, 0, 0);
    }

    #pragma unroll
    for (int mi = 0; mi < 2; ++mi)
        #pragma unroll
        for (int ni = 0; ni < 4; ++ni)
            #pragma unroll
            for (int reg = 0; reg < 4; ++reg) {
                int row = (tma0 + mi) * 16 + g * 4 + reg;
                int col = (tn0 + ni) * 16 + r;
                phi[(size_t)row * 4096 + col] = acc[mi][ni][reg];
            }
}

// ---------------------------------------------------------------------------
extern "C" void kernel_launch(void* const* d_in, const int* in_sizes, int n_in,
                              void* d_out, int out_size, void* d_ws, size_t ws_size,
                              hipStream_t stream) {
    const float* rho = (const float*)d_in[0];   // [1024][4096] f32
    const float* ms  = (const float*)d_in[1];   // [256] f32
    float* phi = (float*)d_out;                 // [1024][4096] f32

    char* ws = (char*)d_ws;
    unsigned short* PA1      = (unsigned short*)(ws);                 //  8 MB
    unsigned short* PB1      = (unsigned short*)(ws + ( 8u << 20));   //  2 MB
    unsigned short* PB2      = (unsigned short*)(ws + (10u << 20));   //  2 MB
    unsigned short* PA2      = (unsigned short*)(ws + (12u << 20));   // .5 MB
    float*          partials = (float*)         (ws + (16u << 20));   // 16 MB

    build_pack <<<3072, 256, 0, stream>>>(rho, ms, PA1, PB1, PB2);
    gemm1      <<<dim3(16, 16), 512, 0, stream>>>(PA1, PB1, partials);
    reduce_pack<<<256, 256, 0, stream>>>(partials, PA2);
    gemm2      <<<dim3(16, 16), 512, 0, stream>>>(PA2, PB2, phi);
}

// Round 5
// 89.854 us; speedup vs baseline: 1.1980x; 1.0064x over previous
//
#include <hip/hip_runtime.h>
#include <hip/hip_bf16.h>

// ---------------------------------------------------------------------------
// phi = (lam ⊙ (rho @ C^T)) @ C, lam zero except k=1..256  => rank-256:
//   A[b,kk]  = Σ_n rho[b,n]·Ck[kk,n]        (kk=0..255, freq=kk+1)
//   phi[b,n] = Σ_kk A[b,kk]·(ms[kk]·Ck[kk,n])
// Ck[kk][n] = sqrt(2/4096)·cos(pi·(2n+1)·(kk+1)/8192)
//
// GEMM B-operands (cos tables) are PRE-PACKED in MFMA fragment order:
//   P[tile][kslice][lane][8 bf16]  -> wave load = one coalesced 1KB dwordx4.
// GEMM1's A-operand is read DIRECTLY from rho (f32) and converted to bf16 in
// registers: lane(r,g) needs rho[tile*16+r][k0+g*8..+7] = two f32x4 loads,
// 16 lanes x 128B = whole cachelines. No LDS, no barriers anywhere.
// Fragment conventions (HW-verified m89):
//   A-frag lane(r=lane&15,g=lane>>4) holds A[row=r][k=g*8+j]
//   B-frag lane(r,g)                holds B[k=g*8+j][col=r]
//   D      lane reg                 holds D[row=g*4+reg][col=r]
// ---------------------------------------------------------------------------

using short8  = __attribute__((ext_vector_type(8))) short;
using ushort8 = __attribute__((ext_vector_type(8))) unsigned short;
using ushort4v= __attribute__((ext_vector_type(4))) unsigned short;
using f32x4   = __attribute__((ext_vector_type(4))) float;

#define KSPLIT 16

static __device__ __forceinline__ unsigned short f32_to_bf16(float f) {
    union { float f; unsigned u; } v; v.f = f;
    unsigned u = v.u;
    u += 0x7FFFu + ((u >> 16) & 1u);   // RNE
    return (unsigned short)(u >> 16);
}

#define DCT_SCALE 0.0220970869120796f     /* sqrt(2/4096) */
#define DCT_W     3.834951969714103e-4f   /* 2*pi/16384   */

// ---------------------------------------------------------------------------
// K1: build packed cos tables only (4 MB writes, 2M cos).
//  PB1[t=16 ][ns=128][lane][8] = bf16(Ck[t*16+r][ns*32+g*8+j])          (B of GEMM1)
//  PB2[tn=256][ks=8 ][lane][8] = bf16(ms[ks*32+g*8+j]·Ck[..][tn*16+r])  (B of GEMM2)
// grid 1024x256: blocks [0,512) PB1, [512,1024) PB2.
// ---------------------------------------------------------------------------
__global__ __launch_bounds__(256) void build_tables(const float* __restrict__ ms,
                                                    unsigned short* __restrict__ PB1,
                                                    unsigned short* __restrict__ PB2) {
    const int bid = blockIdx.x, tid = threadIdx.x;
    if (bid < 512) {           // ---- PB1
        int o8   = bid * 256 + tid;            // 0 .. 131071
        int lane = o8 & 63;
        int ns   = (o8 >> 6) & 127;
        int t    = o8 >> 13;
        int kk   = t * 16 + (lane & 15);
        int nb   = ns * 32 + (lane >> 4) * 8;
        ushort8 h;
        #pragma unroll
        for (int j = 0; j < 8; ++j) {
            int m = ((2 * (nb + j) + 1) * (kk + 1)) & 16383;
            h[j] = f32_to_bf16(DCT_SCALE * __cosf((float)m * DCT_W));
        }
        *(ushort8*)(PB1 + (size_t)o8 * 8) = h;
    } else {                   // ---- PB2 (ms folded in)
        int o8   = (bid - 512) * 256 + tid;    // 0 .. 131071
        int lane = o8 & 63;
        int ks   = (o8 >> 6) & 7;
        int tn   = o8 >> 9;
        int n    = tn * 16 + (lane & 15);
        int kb   = ks * 32 + (lane >> 4) * 8;
        f32x4 m0 = *(const f32x4*)(ms + kb);
        f32x4 m1 = *(const f32x4*)(ms + kb + 4);
        ushort8 h;
        #pragma unroll
        for (int j = 0; j < 8; ++j) {
            int kk = kb + j;
            int m  = ((2 * n + 1) * (kk + 1)) & 16383;
            float msv = (j < 4) ? m0[j & 3] : m1[j & 3];
            h[j] = f32_to_bf16(msv * DCT_SCALE * __cosf((float)m * DCT_W));
        }
        *(ushort8*)(PB2 + (size_t)o8 * 8) = h;
    }
}

// ---------------------------------------------------------------------------
// K2: GEMM1  partials[z][b][kk] = Σ_{n in chunk z} rho[b,n]·Ck[kk,n]
// grid (32,16) x 256 thr: block = 32 rows x 256 kk, K-chunk 256 (8 x BK32).
// 4 waves (wn=0..3), each 32x64 out. A read directly from rho (f32->bf16 in
// reg); B from packed PB1. Pure-register, no LDS, no barriers.
// ---------------------------------------------------------------------------
__global__ __launch_bounds__(256) void gemm1(const float* __restrict__ rho,
                                             const unsigned short* __restrict__ PB1,
                                             float* __restrict__ partials) {
    const int tid  = threadIdx.x;
    const int wn = tid >> 6, lane = tid & 63;
    const int r = lane & 15, g = lane >> 4;
    const int z = blockIdx.y;
    const int row0 = blockIdx.x * 32;

    f32x4 acc[2][4];
    #pragma unroll
    for (int i = 0; i < 2; ++i)
        #pragma unroll
        for (int j = 0; j < 4; ++j)
            acc[i][j] = (f32x4){0.f, 0.f, 0.f, 0.f};

    const float* aptr0 = rho + (size_t)(row0 +      r) * 4096 + z * 256 + g * 8;
    const float* aptr1 = rho + (size_t)(row0 + 16 + r) * 4096 + z * 256 + g * 8;
    const unsigned short* bbase = PB1 + (((size_t)(wn * 4) * 128 + z * 8) * 64 + lane) * 8;

    #pragma unroll
    for (int ks = 0; ks < 8; ++ks) {
        f32x4 a00 = *(const f32x4*)(aptr0 + ks * 32);
        f32x4 a01 = *(const f32x4*)(aptr0 + ks * 32 + 4);
        f32x4 a10 = *(const f32x4*)(aptr1 + ks * 32);
        f32x4 a11 = *(const f32x4*)(aptr1 + ks * 32 + 4);
        ushort8 ua, ub;
        ua[0] = f32_to_bf16(a00[0]); ua[1] = f32_to_bf16(a00[1]);
        ua[2] = f32_to_bf16(a00[2]); ua[3] = f32_to_bf16(a00[3]);
        ua[4] = f32_to_bf16(a01[0]); ua[5] = f32_to_bf16(a01[1]);
        ua[6] = f32_to_bf16(a01[2]); ua[7] = f32_to_bf16(a01[3]);
        ub[0] = f32_to_bf16(a10[0]); ub[1] = f32_to_bf16(a10[1]);
        ub[2] = f32_to_bf16(a10[2]); ub[3] = f32_to_bf16(a10[3]);
        ub[4] = f32_to_bf16(a11[0]); ub[5] = f32_to_bf16(a11[1]);
        ub[6] = f32_to_bf16(a11[2]); ub[7] = f32_to_bf16(a11[3]);
        short8 a0 = (short8)ua, a1 = (short8)ub;
        short8 b[4];
        #pragma unroll
        for (int ni = 0; ni < 4; ++ni)
            b[ni] = *(const short8*)(bbase + ((size_t)ni * 128 + ks) * 64 * 8);
        #pragma unroll
        for (int ni = 0; ni < 4; ++ni) {
            acc[0][ni] = __builtin_amdgcn_mfma_f32_16x16x32_bf16(a0, b[ni], acc[0][ni], 0, 0, 0);
            acc[1][ni] = __builtin_amdgcn_mfma_f32_16x16x32_bf16(a1, b[ni], acc[1][ni], 0, 0, 0);
        }
    }

    float* outp = partials + (size_t)z * 262144;
    #pragma unroll
    for (int mi = 0; mi < 2; ++mi)
        #pragma unroll
        for (int ni = 0; ni < 4; ++ni)
            #pragma unroll
            for (int reg = 0; reg < 4; ++reg) {
                int row = row0 + mi * 16 + g * 4 + reg;
                int col = (wn * 4 + ni) * 16 + r;
                outp[(size_t)row * 256 + col] = acc[mi][ni][reg];
            }
}

// ---------------------------------------------------------------------------
// K3: reduce split-K partials -> PA2 packed bf16 (ms folded into PB2).
//  PA2[tma=64][ks=8][lane][8] = bf16(Σ_z partials[z][tma*16+r][ks*32+g*8+j])
// ---------------------------------------------------------------------------
__global__ __launch_bounds__(256) void reduce_pack(const float* __restrict__ partials,
                                                   unsigned short* __restrict__ PA2) {
    int idx = blockIdx.x * 256 + threadIdx.x;  // 0..65535
    int kk4 = idx & 63, b = idx >> 6;
    int kk  = kk4 * 4;
    f32x4 s = (f32x4){0.f, 0.f, 0.f, 0.f};
    #pragma unroll
    for (int z = 0; z < KSPLIT; ++z)
        s += *(const f32x4*)(partials + (size_t)z * 262144 + (size_t)b * 256 + kk);
    int tma = b >> 4, r = b & 15;
    int ks = kk >> 5, rem = kk & 31, g = rem >> 3, h = (rem >> 2) & 1;
    size_t slot = (((size_t)tma * 8 + ks) * 64 + g * 16 + r) * 8 + h * 4;
    ushort4v o;
    o[0] = f32_to_bf16(s[0]); o[1] = f32_to_bf16(s[1]);
    o[2] = f32_to_bf16(s[2]); o[3] = f32_to_bf16(s[3]);
    *(ushort4v*)(PA2 + slot) = o;
}

// ---------------------------------------------------------------------------
// K4: GEMM2  phi[b][n] = Σ_kk A[b,kk]·(ms·Ck)[kk,n]
// grid (16,16) x 512 thr: block = 64 rows x 256 n-cols, K=256 (8 x BK32).
// Pure-register, no LDS, no barriers.
// ---------------------------------------------------------------------------
__global__ __launch_bounds__(512) void gemm2(const unsigned short* __restrict__ PA2,
                                             const unsigned short* __restrict__ PB2,
                                             float* __restrict__ phi) {
    const int tid  = threadIdx.x;
    const int wave = tid >> 6, lane = tid & 63;
    const int wm = wave >> 2, wn = wave & 3;
    const int r = lane & 15, g = lane >> 4;
    const int tma0 = blockIdx.x * 4 + wm * 2;
    const int tn0  = blockIdx.y * 16 + wn * 4;

    f32x4 acc[2][4];
    #pragma unroll
    for (int i = 0; i < 2; ++i)
        #pragma unroll
        for (int j = 0; j < 4; ++j)
            acc[i][j] = (f32x4){0.f, 0.f, 0.f, 0.f};

    #pragma unroll
    for (int ks = 0; ks < 8; ++ks) {
        short8 a[2], b[4];
        #pragma unroll
        for (int mi = 0; mi < 2; ++mi)
            a[mi] = *(const short8*)(PA2 + (((size_t)(tma0 + mi) * 8 + ks) * 64 + lane) * 8);
        #pragma unroll
        for (int ni = 0; ni < 4; ++ni)
            b[ni] = *(const short8*)(PB2 + (((size_t)(tn0 + ni) * 8 + ks) * 64 + lane) * 8);
        #pragma unroll
        for (int mi = 0; mi < 2; ++mi)
            #pragma unroll
            for (int ni = 0; ni < 4; ++ni)
                acc[mi][ni] = __builtin_amdgcn_mfma_f32_16x16x32_bf16(a[mi], b[ni], acc[mi][ni], 0, 0, 0);
    }

    #pragma unroll
    for (int mi = 0; mi < 2; ++mi)
        #pragma unroll
        for (int ni = 0; ni < 4; ++ni)
            #pragma unroll
            for (int reg = 0; reg < 4; ++reg) {
                int row = (tma0 + mi) * 16 + g * 4 + reg;
                int col = (tn0 + ni) * 16 + r;
                phi[(size_t)row * 4096 + col] = acc[mi][ni][reg];
            }
}

// ---------------------------------------------------------------------------
extern "C" void kernel_launch(void* const* d_in, const int* in_sizes, int n_in,
                              void* d_out, int out_size, void* d_ws, size_t ws_size,
                              hipStream_t stream) {
    const float* rho = (const float*)d_in[0];   // [1024][4096] f32
    const float* ms  = (const float*)d_in[1];   // [256] f32
    float* phi = (float*)d_out;                 // [1024][4096] f32

    char* ws = (char*)d_ws;
    unsigned short* PB1      = (unsigned short*)(ws);                 //  2 MB
    unsigned short* PB2      = (unsigned short*)(ws + (2u << 20));    //  2 MB
    unsigned short* PA2      = (unsigned short*)(ws + (4u << 20));    // .5 MB
    float*          partials = (float*)         (ws + (8u << 20));    // 16 MB

    build_tables<<<1024, 256, 0, stream>>>(ms, PB1, PB2);
    gemm1       <<<dim3(32, 16), 256, 0, stream>>>(rho, PB1, partials);
    reduce_pack <<<256, 256, 0, stream>>>(partials, PA2);
    gemm2       <<<dim3(16, 16), 512, 0, stream>>>(PA2, PB2, phi);
}

// Round 6
// 88.204 us; speedup vs baseline: 1.2204x; 1.0187x over previous
//
#include <hip/hip_runtime.h>
#include <hip/hip_bf16.h>

// ---------------------------------------------------------------------------
// phi = (lam ⊙ (rho @ C^T)) @ C, lam zero except k=1..256  => rank-256:
//   A[b,kk]  = Σ_n rho[b,n]·Ck[kk,n]        (kk=0..255, freq=kk+1)
//   phi[b,n] = Σ_kk A[b,kk]·(ms[kk]·Ck[kk,n])
// Ck[kk][n] = sqrt(2/4096)·cos(pi·(2n+1)·(kk+1)/8192)
//
// Cos tables PRE-PACKED in MFMA fragment order: P[tile][kslice][lane][8 bf16].
// GEMM1 stages its rho K-chunk through LDS once (coalesced f32x4 loads,
// ONE barrier per kernel), then runs a pure-register MFMA loop.
// Split-K partials are bf16 (error budget: +2.8e-3 RSS on A's 5.7e-3).
// Fragment conventions (HW-verified m89):
//   A-frag lane(r=lane&15,g=lane>>4) holds A[row=r][k=g*8+j]
//   B-frag lane(r,g)                holds B[k=g*8+j][col=r]
//   D      lane reg                 holds D[row=g*4+reg][col=r]
// ---------------------------------------------------------------------------

using short8  = __attribute__((ext_vector_type(8))) short;
using ushort8 = __attribute__((ext_vector_type(8))) unsigned short;
using ushort4v= __attribute__((ext_vector_type(4))) unsigned short;
using f32x4   = __attribute__((ext_vector_type(4))) float;

#define KSPLIT 16

static __device__ __forceinline__ unsigned short f32_to_bf16(float f) {
    union { float f; unsigned u; } v; v.f = f;
    unsigned u = v.u;
    u += 0x7FFFu + ((u >> 16) & 1u);   // RNE
    return (unsigned short)(u >> 16);
}
static __device__ __forceinline__ float bf16_to_f32(unsigned short h) {
    union { unsigned u; float f; } v; v.u = ((unsigned)h) << 16;
    return v.f;
}

#define DCT_SCALE 0.0220970869120796f     /* sqrt(2/4096) */
#define DCT_W     3.834951969714103e-4f   /* 2*pi/16384   */

// ---------------------------------------------------------------------------
// K1: build packed cos tables (4 MB writes, 2M cos).
//  PB1[t=16 ][ns=128][lane][8] = bf16(Ck[t*16+r][ns*32+g*8+j])          (B of GEMM1)
//  PB2[tn=256][ks=8 ][lane][8] = bf16(ms[ks*32+g*8+j]·Ck[..][tn*16+r])  (B of GEMM2)
// grid 1024x256: blocks [0,512) PB1, [512,1024) PB2.
// ---------------------------------------------------------------------------
__global__ __launch_bounds__(256) void build_tables(const float* __restrict__ ms,
                                                    unsigned short* __restrict__ PB1,
                                                    unsigned short* __restrict__ PB2) {
    const int bid = blockIdx.x, tid = threadIdx.x;
    if (bid < 512) {           // ---- PB1
        int o8   = bid * 256 + tid;            // 0 .. 131071
        int lane = o8 & 63;
        int ns   = (o8 >> 6) & 127;
        int t    = o8 >> 13;
        int kk   = t * 16 + (lane & 15);
        int nb   = ns * 32 + (lane >> 4) * 8;
        ushort8 h;
        #pragma unroll
        for (int j = 0; j < 8; ++j) {
            int m = ((2 * (nb + j) + 1) * (kk + 1)) & 16383;
            h[j] = f32_to_bf16(DCT_SCALE * __cosf((float)m * DCT_W));
        }
        *(ushort8*)(PB1 + (size_t)o8 * 8) = h;
    } else {                   // ---- PB2 (ms folded in)
        int o8   = (bid - 512) * 256 + tid;    // 0 .. 131071
        int lane = o8 & 63;
        int ks   = (o8 >> 6) & 7;
        int tn   = o8 >> 9;
        int n    = tn * 16 + (lane & 15);
        int kb   = ks * 32 + (lane >> 4) * 8;
        f32x4 m0 = *(const f32x4*)(ms + kb);
        f32x4 m1 = *(const f32x4*)(ms + kb + 4);
        ushort8 h;
        #pragma unroll
        for (int j = 0; j < 8; ++j) {
            int kk = kb + j;
            int m  = ((2 * n + 1) * (kk + 1)) & 16383;
            float msv = (j < 4) ? m0[j & 3] : m1[j & 3];
            h[j] = f32_to_bf16(msv * DCT_SCALE * __cosf((float)m * DCT_W));
        }
        *(ushort8*)(PB2 + (size_t)o8 * 8) = h;
    }
}

// ---------------------------------------------------------------------------
// K2: GEMM1  partials[z][b][kk] = Σ_{n in chunk z} rho[b,n]·Ck[kk,n]  (bf16)
// grid (32,16) x 256 thr: block = 32 rows x 256 kk, K-chunk 256 (8 x BK32).
// Stage rho chunk coalesced -> LDS [32][264] bf16 (528B rows: 16B-aligned,
// fragment b128 reads land 8 dwords/bank = conflict-free). ONE barrier.
// ---------------------------------------------------------------------------
__global__ __launch_bounds__(256) void gemm1(const float* __restrict__ rho,
                                             const unsigned short* __restrict__ PB1,
                                             unsigned short* __restrict__ partials) {
    __shared__ unsigned short As[32][264];   // pad 256->264 (stride 528 B)

    const int tid = threadIdx.x;
    const int wn = tid >> 6, lane = tid & 63;
    const int r = lane & 15, g = lane >> 4;
    const int z = blockIdx.y;
    const int row0 = blockIdx.x * 32;

    // ---- stage 32 rows x 256 f32 -> bf16 LDS, fully coalesced (8 passes)
    #pragma unroll
    for (int s = 0; s < 8; ++s) {
        int slot = tid + s * 256;          // 0..2047
        int row = slot >> 6, qd = slot & 63;
        f32x4 v = *(const f32x4*)(rho + (size_t)(row0 + row) * 4096 + z * 256 + qd * 4);
        ushort4v h;
        h[0] = f32_to_bf16(v[0]); h[1] = f32_to_bf16(v[1]);
        h[2] = f32_to_bf16(v[2]); h[3] = f32_to_bf16(v[3]);
        *(ushort4v*)&As[row][qd * 4] = h;
    }
    __syncthreads();

    f32x4 acc[2][4];
    #pragma unroll
    for (int i = 0; i < 2; ++i)
        #pragma unroll
        for (int j = 0; j < 4; ++j)
            acc[i][j] = (f32x4){0.f, 0.f, 0.f, 0.f};

    const unsigned short* bbase = PB1 + (((size_t)(wn * 4) * 128 + z * 8) * 64 + lane) * 8;

    #pragma unroll
    for (int ks = 0; ks < 8; ++ks) {
        short8 a0 = *(const short8*)&As[     r][ks * 32 + g * 8];
        short8 a1 = *(const short8*)&As[16 + r][ks * 32 + g * 8];
        short8 b[4];
        #pragma unroll
        for (int ni = 0; ni < 4; ++ni)
            b[ni] = *(const short8*)(bbase + ((size_t)ni * 128 + ks) * 64 * 8);
        #pragma unroll
        for (int ni = 0; ni < 4; ++ni) {
            acc[0][ni] = __builtin_amdgcn_mfma_f32_16x16x32_bf16(a0, b[ni], acc[0][ni], 0, 0, 0);
            acc[1][ni] = __builtin_amdgcn_mfma_f32_16x16x32_bf16(a1, b[ni], acc[1][ni], 0, 0, 0);
        }
    }

    unsigned short* outp = partials + (size_t)z * 262144;
    #pragma unroll
    for (int mi = 0; mi < 2; ++mi)
        #pragma unroll
        for (int ni = 0; ni < 4; ++ni)
            #pragma unroll
            for (int reg = 0; reg < 4; ++reg) {
                int row = row0 + mi * 16 + g * 4 + reg;
                int col = (wn * 4 + ni) * 16 + r;
                outp[(size_t)row * 256 + col] = f32_to_bf16(acc[mi][ni][reg]);
            }
}

// ---------------------------------------------------------------------------
// K3: reduce bf16 split-K partials (f32 accum) -> PA2 packed bf16.
//  PA2[tma=64][ks=8][lane][8] = bf16(Σ_z partials[z][tma*16+r][ks*32+g*8+j])
// ---------------------------------------------------------------------------
__global__ __launch_bounds__(256) void reduce_pack(const unsigned short* __restrict__ partials,
                                                   unsigned short* __restrict__ PA2) {
    int idx = blockIdx.x * 256 + threadIdx.x;  // 0..65535
    int kk4 = idx & 63, b = idx >> 6;
    int kk  = kk4 * 4;
    float s0 = 0.f, s1 = 0.f, s2 = 0.f, s3 = 0.f;
    #pragma unroll
    for (int z = 0; z < KSPLIT; ++z) {
        ushort4v v = *(const ushort4v*)(partials + (size_t)z * 262144 + (size_t)b * 256 + kk);
        s0 += bf16_to_f32(v[0]); s1 += bf16_to_f32(v[1]);
        s2 += bf16_to_f32(v[2]); s3 += bf16_to_f32(v[3]);
    }
    int tma = b >> 4, r = b & 15;
    int ks = kk >> 5, rem = kk & 31, g = rem >> 3, h = (rem >> 2) & 1;
    size_t slot = (((size_t)tma * 8 + ks) * 64 + g * 16 + r) * 8 + h * 4;
    ushort4v o;
    o[0] = f32_to_bf16(s0); o[1] = f32_to_bf16(s1);
    o[2] = f32_to_bf16(s2); o[3] = f32_to_bf16(s3);
    *(ushort4v*)(PA2 + slot) = o;
}

// ---------------------------------------------------------------------------
// K4: GEMM2  phi[b][n] = Σ_kk A[b,kk]·(ms·Ck)[kk,n]
// grid (16,16) x 512 thr: block = 64 rows x 256 n-cols, K=256 (8 x BK32).
// Pure-register, no LDS, no barriers.
// ---------------------------------------------------------------------------
__global__ __launch_bounds__(512) void gemm2(const unsigned short* __restrict__ PA2,
                                             const unsigned short* __restrict__ PB2,
                                             float* __restrict__ phi) {
    const int tid  = threadIdx.x;
    const int wave = tid >> 6, lane = tid & 63;
    const int wm = wave >> 2, wn = wave & 3;
    const int r = lane & 15, g = lane >> 4;
    const int tma0 = blockIdx.x * 4 + wm * 2;
    const int tn0  = blockIdx.y * 16 + wn * 4;

    f32x4 acc[2][4];
    #pragma unroll
    for (int i = 0; i < 2; ++i)
        #pragma unroll
        for (int j = 0; j < 4; ++j)
            acc[i][j] = (f32x4){0.f, 0.f, 0.f, 0.f};

    #pragma unroll
    for (int ks = 0; ks < 8; ++ks) {
        short8 a[2], b[4];
        #pragma unroll
        for (int mi = 0; mi < 2; ++mi)
            a[mi] = *(const short8*)(PA2 + (((size_t)(tma0 + mi) * 8 + ks) * 64 + lane) * 8);
        #pragma unroll
        for (int ni = 0; ni < 4; ++ni)
            b[ni] = *(const short8*)(PB2 + (((size_t)(tn0 + ni) * 8 + ks) * 64 + lane) * 8);
        #pragma unroll
        for (int mi = 0; mi < 2; ++mi)
            #pragma unroll
            for (int ni = 0; ni < 4; ++ni)
                acc[mi][ni] = __builtin_amdgcn_mfma_f32_16x16x32_bf16(a[mi], b[ni], acc[mi][ni], 0, 0, 0);
    }

    #pragma unroll
    for (int mi = 0; mi < 2; ++mi)
        #pragma unroll
        for (int ni = 0; ni < 4; ++ni)
            #pragma unroll
            for (int reg = 0; reg < 4; ++reg) {
                int row = (tma0 + mi) * 16 + g * 4 + reg;
                int col = (tn0 + ni) * 16 + r;
                phi[(size_t)row * 4096 + col] = acc[mi][ni][reg];
            }
}

// ---------------------------------------------------------------------------
extern "C" void kernel_launch(void* const* d_in, const int* in_sizes, int n_in,
                              void* d_out, int out_size, void* d_ws, size_t ws_size,
                              hipStream_t stream) {
    const float* rho = (const float*)d_in[0];   // [1024][4096] f32
    const float* ms  = (const float*)d_in[1];   // [256] f32
    float* phi = (float*)d_out;                 // [1024][4096] f32

    char* ws = (char*)d_ws;
    unsigned short* PB1      = (unsigned short*)(ws);                 //  2 MB
    unsigned short* PB2      = (unsigned short*)(ws + (2u << 20));    //  2 MB
    unsigned short* PA2      = (unsigned short*)(ws + (4u << 20));    // .5 MB
    unsigned short* partials = (unsigned short*)(ws + (8u << 20));    //  8 MB bf16

    build_tables<<<1024, 256, 0, stream>>>(ms, PB1, PB2);
    gemm1       <<<dim3(32, 16), 256, 0, stream>>>(rho, PB1, partials);
    reduce_pack <<<256, 256, 0, stream>>>(partials, PA2);
    gemm2       <<<dim3(16, 16), 512, 0, stream>>>(PA2, PB2, phi);
}